// Round 2
// baseline (363.604 us; speedup 1.0000x reference)
//
#include <hip/hip_runtime.h>

// Problem constants (match reference setup_inputs / module constants)
#define BB 16
#define LL 4096
#define GG 256
#define RR 84
#define WW 169      // 2*R+1
#define DD 12
#define VOCAB 25    // 2*D+1

// Output element offsets (int32 elements, concat in return order)
#define S_L2L (BB * LL * WW)   // 11,075,584
#define S_G2G (BB * GG * GG)   //  1,048,576
#define S_L2G (BB * LL * GG)   // 16,777,216
#define S_G2L (BB * GG * LL)   // 16,777,216
#define OFF0 0
#define OFF1 (OFF0 + S_L2L)
#define OFF2 (OFF1 + S_G2G)
#define OFF3 (OFF2 + S_L2G)
#define OFF4 (OFF3 + S_L2L)
#define OFF5 (OFF4 + S_L2L)
#define OFF6 (OFF5 + S_G2G)
#define OFF7 (OFF6 + S_L2G)
// NOTE: OFF4 must be OFF3 + S_G2L (sizes differ!) — define explicitly:
#undef OFF4
#undef OFF5
#undef OFF6
#undef OFF7
#define OFF4 (OFF3 + S_G2L)
#define OFF5 (OFF4 + S_L2L)
#define OFF6 (OFF5 + S_G2G)
#define OFF7 (OFF6 + S_L2G)

// Grid-stride persistent writer: super-chunks of 2048 elements per stream;
// each 256-thread block handles one super-chunk per loop iteration
// (2 int4 per thread per stream = 4 NT stores in flight).
#define NC_L2L (S_L2L / 2048)   // 5408
#define NC_G2G (S_G2G / 2048)   //  512
#define NC_L2G (S_L2G / 2048)   // 8192
#define NC_G2L (S_G2L / 2048)   // 8192
#define NC_TOTAL (NC_L2L + NC_G2G + NC_L2G + NC_G2L)  // 22304
#define GRID_WRITER 2560        // 10 blocks/CU queued; grid-stride covers rest

// Non-temporal int4 store: output is write-once, never re-read by us.
typedef int v4i __attribute__((ext_vector_type(4)));
static __device__ __forceinline__ void nt_store4(int* p, int a, int b, int c, int d) {
    v4i v = {a, b, c, d};
    __builtin_nontemporal_store(v, (v4i*)p);
}

// -------- suffix-cumsum kernel: one block (256 threads) per batch --------
__global__ __launch_bounds__(256) void scan_kernel(
        const int* __restrict__ long_bp,
        const int* __restrict__ glob_bp,
        int* __restrict__ long_seg,
        int* __restrict__ glob_seg) {
    const int b = blockIdx.x;
    const int t = threadIdx.x;          // 256 threads
    const int lane = t & 63;
    const int wv = t >> 6;              // 4 waves
    __shared__ int wsA[4];              // long wave sums
    __shared__ int wsB[4];              // glob wave sums

    // ---- long: 16 consecutive elems per thread, vectorized ----
    const int4* bp4 = (const int4*)(long_bp + b * LL) + t * 4;
    int4 v[4];
#pragma unroll
    for (int j = 0; j < 4; ++j) v[j] = bp4[j];
    int vals[16];
#pragma unroll
    for (int j = 0; j < 4; ++j) {
        vals[4*j+0] = v[j].x; vals[4*j+1] = v[j].y;
        vals[4*j+2] = v[j].z; vals[4*j+3] = v[j].w;
    }
    int s = 0;
#pragma unroll
    for (int j = 0; j < 16; ++j) s += vals[j];

    int sc = s;
#pragma unroll
    for (int off = 1; off < 64; off <<= 1) {
        int n = __shfl_up(sc, off, 64);
        if (lane >= off) sc += n;
    }
    if (lane == 63) wsA[wv] = sc;

    const int gv = glob_bp[b * GG + t];
    int gsc = gv;
#pragma unroll
    for (int off = 1; off < 64; off <<= 1) {
        int n = __shfl_up(gsc, off, 64);
        if (lane >= off) gsc += n;
    }
    if (lane == 63) wsB[wv] = gsc;

    __syncthreads();   // the only barrier

    int beforeA = 0, beforeB = 0;
#pragma unroll
    for (int w = 0; w < 4; ++w) {
        if (w < wv) { beforeA += wsA[w]; beforeB += wsB[w]; }
    }
    const int totalA = wsA[0] + wsA[1] + wsA[2] + wsA[3];
    const int totalB = wsB[0] + wsB[1] + wsB[2] + wsB[3];

    int run = beforeA + (sc - s);        // exclusive prefix at chunk start
    int4* seg4 = (int4*)(long_seg + b * LL) + t * 4;
#pragma unroll
    for (int j = 0; j < 4; ++j) {
        int4 o;
        o.x = totalA - run; run += vals[4*j+0];
        o.y = totalA - run; run += vals[4*j+1];
        o.z = totalA - run; run += vals[4*j+2];
        o.w = totalA - run; run += vals[4*j+3];
        seg4[j] = o;                     // normal store: re-read by fused_writer
    }
    glob_seg[b * GG + t] = totalB - (beforeB + (gsc - gv));
}

// -------- per-stream element writers (branchless, 4 elems / call) --------

static __device__ __forceinline__ void do_l2l(const int* __restrict__ long_seg,
                                              int* __restrict__ out, unsigned f) {
    // flat over (b*L + i) * 169 + k; a 4-elem group spans at most 2 rows.
    const unsigned row0 = f / (unsigned)WW;
    const int k0 = (int)(f - row0 * (unsigned)WW);
    const unsigned row3 = (f + 3u) / (unsigned)WW;
    const int i0 = (int)(row0 & (LL - 1));
    const int i3 = (int)(row3 & (LL - 1));
    const int seg0 = long_seg[row0];
    const int seg3 = long_seg[row3];
    int m[4], r[4];
#pragma unroll
    for (int e = 0; e < 4; ++e) {
        const int kk = k0 + e;
        const bool wrap = (kk >= WW);
        const int k = wrap ? kk - WW : kk;
        const unsigned row = wrap ? row3 : row0;
        const int i = wrap ? i3 : i0;
        const int segi = wrap ? seg3 : seg0;
        const int j = i + k - RR;
        int msk = 0;
        if (j >= 0 && j < LL)
            msk = (long_seg[row - (unsigned)i + (unsigned)j] == segi) ? 1 : 0;
        int c = k - RR;
        c = c < -DD ? -DD : (c > DD ? DD : c);
        r[e] = (c >= 0) ? c : (DD - c);
        m[e] = msk;
    }
    nt_store4(out + OFF0 + f, m[0], m[1], m[2], m[3]);
    nt_store4(out + OFF4 + f, r[0], r[1], r[2], r[3]);
}

static __device__ __forceinline__ void do_g2g(const int* __restrict__ glob_seg,
                                              int* __restrict__ out, unsigned f) {
    const int h0 = (int)(f & (GG - 1));       // multiple of 4
    const unsigned row = f >> 8;              // b*G + g
    const int g = (int)(row & (GG - 1));
    const int segg = glob_seg[row];
    const int tokg = segg > 0 ? 1 : 0;
    const int4 sh = *(const int4*)(glob_seg + (row - (unsigned)g) + (unsigned)h0);
    const int sgh[4] = {sh.x, sh.y, sh.z, sh.w};
    int m[4], r[4];
#pragma unroll
    for (int e = 0; e < 4; ++e) {
        const int tokh = sgh[e] > 0 ? 1 : 0;
        int c = (h0 + e) - g;
        c = c < -DD ? -DD : (c > DD ? DD : c);
        const int r0 = (c >= 0) ? c : (DD - c);
        m[e] = (tokg == tokh) ? 1 : 0;
        r[e] = (segg == sgh[e]) ? r0 : (VOCAB + 2);
    }
    nt_store4(out + OFF1 + f, m[0], m[1], m[2], m[3]);
    nt_store4(out + OFF5 + f, r[0], r[1], r[2], r[3]);
}

static __device__ __forceinline__ void do_l2g(const int* __restrict__ long_seg,
                                              const int* __restrict__ long_pid,
                                              const int* __restrict__ glob_seg,
                                              int* __restrict__ out, unsigned f) {
    const int g0 = (int)(f & (GG - 1));       // multiple of 4
    const unsigned row = f >> 8;              // b*L + i
    const int b = (int)(row >> 12);
    const int tokl = long_seg[row] > 0 ? 1 : 0;
    const int pid = long_pid[row];
    const int4 sg = *(const int4*)(glob_seg + b * GG + g0);
    const int sgv[4] = {sg.x, sg.y, sg.z, sg.w};
    int m[4], r[4];
#pragma unroll
    for (int e = 0; e < 4; ++e) {
        const int tokg = sgv[e] > 0 ? 1 : 0;
        const int eq = (pid == (g0 + e)) ? 1 : 0;
        m[e] = (tokl == tokg) ? eq : 0;
        r[e] = eq + VOCAB;
    }
    nt_store4(out + OFF2 + f, m[0], m[1], m[2], m[3]);
    nt_store4(out + OFF6 + f, r[0], r[1], r[2], r[3]);
}

static __device__ __forceinline__ void do_g2l(const int* __restrict__ long_seg,
                                              const int* __restrict__ long_pid,
                                              const int* __restrict__ glob_seg,
                                              int* __restrict__ out, unsigned f) {
    const int i0 = (int)(f & (LL - 1));       // multiple of 4
    const unsigned row = f >> 12;             // b*G + g
    const int g = (int)(row & (GG - 1));
    const int b = (int)(row >> 8);
    const int tokg = glob_seg[row] > 0 ? 1 : 0;
    const int4 pid4 = *(const int4*)(long_pid + b * LL + i0);
    const int4 seg4 = *(const int4*)(long_seg + b * LL + i0);
    const int pidv[4] = {pid4.x, pid4.y, pid4.z, pid4.w};
    const int segv[4] = {seg4.x, seg4.y, seg4.z, seg4.w};
    const int gz = (g == 0) ? 1 : 0;
    int m[4], r[4];
#pragma unroll
    for (int e = 0; e < 4; ++e) {
        const int tokl = segv[e] > 0 ? 1 : 0;
        const int eq = (g == pidv[e]) ? 1 : 0;
        const int allow = eq | gz;
        m[e] = (tokl == tokg) ? allow : 0;
        r[e] = eq + VOCAB;
    }
    nt_store4(out + OFF3 + f, m[0], m[1], m[2], m[3]);
    nt_store4(out + OFF7 + f, r[0], r[1], r[2], r[3]);
}

// -------- grid-stride persistent fused writer ----------------------------
__global__ __launch_bounds__(256) void fused_writer(
        const int* __restrict__ long_seg,
        const int* __restrict__ long_pid,
        const int* __restrict__ glob_seg,
        int* __restrict__ out) {
    const unsigned tid4 = (unsigned)threadIdx.x * 4u;
    for (unsigned c = blockIdx.x; c < NC_TOTAL; c += gridDim.x) {
        if (c < NC_L2L) {
            const unsigned f = c * 2048u + tid4;
            do_l2l(long_seg, out, f);
            do_l2l(long_seg, out, f + 1024u);
        } else if (c < NC_L2L + NC_G2G) {
            const unsigned f = (c - NC_L2L) * 2048u + tid4;
            do_g2g(glob_seg, out, f);
            do_g2g(glob_seg, out, f + 1024u);
        } else if (c < NC_L2L + NC_G2G + NC_L2G) {
            const unsigned f = (c - (NC_L2L + NC_G2G)) * 2048u + tid4;
            do_l2g(long_seg, long_pid, glob_seg, out, f);
            do_l2g(long_seg, long_pid, glob_seg, out, f + 1024u);
        } else {
            const unsigned f = (c - (NC_L2L + NC_G2G + NC_L2G)) * 2048u + tid4;
            do_g2l(long_seg, long_pid, glob_seg, out, f);
            do_g2l(long_seg, long_pid, glob_seg, out, f + 1024u);
        }
    }
}

extern "C" void kernel_launch(void* const* d_in, const int* in_sizes, int n_in,
                              void* d_out, int out_size, void* d_ws, size_t ws_size,
                              hipStream_t stream) {
    const int* long_bp  = (const int*)d_in[0];  // (B, L)
    const int* long_pid = (const int*)d_in[1];  // (B, L)
    const int* glob_bp  = (const int*)d_in[2];  // (B, G)
    int* out = (int*)d_out;

    // workspace: long_seg (B*L) then glob_seg (B*G) — 278,528 bytes
    int* long_seg = (int*)d_ws;
    int* glob_seg = long_seg + BB * LL;

    scan_kernel<<<BB, 256, 0, stream>>>(long_bp, glob_bp, long_seg, glob_seg);
    fused_writer<<<GRID_WRITER, 256, 0, stream>>>(long_seg, long_pid, glob_seg, out);
}